// Round 7
// baseline (1184.190 us; speedup 1.0000x reference)
//
#include <hip/hip_runtime.h>

// TT embedding lookup, fused single-kernel (binning redone per block).
// P=(216,216,216), Q=(2,4,2), R=(128,128), tables=2, batch=1024.
// core0: [2,216,256]   (A row:  [Q0=2][R0=128])
// core1: [2,216,65536] (Bm row: [R0=128][S=512], S = q1*128 + r1)
// core2: [2,216,256]   (C row:  [R1=128][Q2=2])
// out:   [2,1024,16]
//
// Grid (432 groups, 4 q-quarters, 2 chunk-slots) x 128 threads.
// Work split (round-5 lesson: need deep pipeline AND <=64 VGPR for 8
// waves/SIMD; 112 VGPR halved residency and canceled the pipeline win):
//   lane owns ONE s column (s = q*128 + w*64 + tl) and contracts the FULL
//   r=0..127 range in-register -> acc = 8l x 2q0 = 16 VGPRs, B double-buffer
//   2x8 scalar floats = 16 VGPRs, NO cross-wave r-combine.
// Scan: 16 idx loads issued up-front into regs (kills the 16x serial
// L2-latency chain), then pure-VALU ballot/popcount placement (order
// deterministic -> cs=0/cs=1 blocks see identical lists; round-2 lesson).
//
// [Round-6: container-level infra failure, no kernel data; resubmitted
// unchanged after hang-path audit (uniform early-exit, static indexing).]

#define CAP  48          // Binomial(1024,1/216): mean 4.74, P(m>48) ~ 0
#define CAPP (CAP + 8)   // pad: s_aux[base+l] is read blindly for l<8

__global__ __launch_bounds__(128, 6) void tt_fused(
    const int* __restrict__ idx32,
    const float* __restrict__ c0,
    const float* __restrict__ c1,
    const float* __restrict__ c2,
    float* __restrict__ out)
{
    const int g     = blockIdx.x;      // group id [0,432) = table*216 + i1
    const int q     = blockIdx.y;      // s-quarter {0..3} == q1
    const int cs    = blockIdx.z;      // chunk slot {0,1}
    const int table = g / 216;
    const int i1    = g - table * 216;

    const int tid = threadIdx.x;
    const int w   = tid >> 6;          // wave id (s-half within quarter)
    const int tl  = tid & 63;

    __shared__ float lds[2048];        // A stage: [l][r] -> (A0,A1), 8 KB
    __shared__ float red[2][8][4];     // per-wave epilogue partials
    __shared__ int s_id[CAPP];
    __shared__ int s_aux[CAPP];        // (i0<<16)|i2 ; pad rows -> row 0

    if (tl < CAPP) s_aux[tl] = 0;      // both waves write identical zeros

    // int64-vs-int32 buffer detection (values < 2^31 => odd words zero, LE)
    const bool is64 = (idx32[1] == 0) & (idx32[3] == 0) &
                      (idx32[5] == 0) & (idx32[7] == 0);

    // scan loads: all 16 issued up-front (independent), then VALU-only.
    unsigned v[16];
    if (is64) {
        const long long* p = (const long long*)idx32 + (table << 10) + tl;
#pragma unroll
        for (int it = 0; it < 16; ++it) v[it] = (unsigned)p[it * 64];
    } else {
        const int* p = idx32 + (table << 10) + tl;
#pragma unroll
        for (int it = 0; it < 16; ++it) v[it] = (unsigned)p[it * 64];
    }

    // deterministic placement, j ascending; both waves identical.
    int cnt = 0;
#pragma unroll
    for (int it = 0; it < 16; ++it) {
        const unsigned idx = v[it];
        const unsigned i0  = idx / 46656u;           // magic-mul (idx < 2^24)
        const unsigned rem = idx - i0 * 46656u;
        const unsigned bi1 = rem / 216u;
        const bool match = ((int)bi1 == i1);
        const unsigned long long mask = __ballot(match);
        if (match) {
            const int pos = cnt + __popcll(mask & ((1ull << tl) - 1ull));
            if (pos < CAP) {
                const unsigned i2 = rem - bi1 * 216u;
                s_id[pos]  = (table << 10) + it * 64 + tl;
                s_aux[pos] = (int)((i0 << 16) | i2);
            }
        }
        cnt += (int)__popcll(mask);                  // uniform across wave
    }
    const int m = min(cnt, CAP);
    if (m <= cs * 8) return;           // uniform per block; cs=1 mostly exits
    __syncthreads();                   // order cross-wave pad/scan writes

    float2*       lds2 = (float2*)lds;
    const float4* lds4 = (const float4*)lds;

    // lane's B column: element [r][s] of row g at r*512 + s
    const float* bcol = c1 + ((size_t)g << 16) + (size_t)(q * 128 + w * 64 + tl);
    const float* c0t  = c0 + (size_t)table * 216 * 256;

    // B double-buffer: batch T covers r = T*8 .. T*8+7 (contiguous 256B/inst)
#define LOADB(BUF, T)                                                       \
    _Pragma("unroll")                                                       \
    for (int i = 0; i < 8; ++i) BUF[i] = bcol[(size_t)((T) * 8 + i) * 512];

#define FMAB(BUF, T)                                                        \
    _Pragma("unroll")                                                       \
    for (int j = 0; j < 4; ++j) {                                           \
        const float b0 = BUF[2 * j];                                        \
        const float b1 = BUF[2 * j + 1];                                    \
        _Pragma("unroll")                                                   \
        for (int l = 0; l < 8; ++l) {                                       \
            const float4 av = lds4[l * 64 + (T) * 4 + j];                   \
            /* av = (A0[r],A1[r],A0[r+1],A1[r+1]) broadcast */              \
            acc0[l] += av.x * b0 + av.z * b1;                               \
            acc1[l] += av.y * b0 + av.w * b1;                               \
        }                                                                   \
    }

    for (int base = cs * 8; base < m; base += 16) {
        const int cl = min(8, m - base);
        __syncthreads();               // previous pass's LDS reads done

        // stage A through regs: thread owns r=tid (both waves cover 0..127)
        float a0[8], a1[8];
#pragma unroll
        for (int l = 0; l < 8; ++l) {
            const float* ar = c0t + (size_t)(s_aux[base + l] >> 16) * 256;
            a0[l] = ar[tid];           // q0=0
            a1[l] = ar[tid + 128];     // q0=1
        }
        float bva[8], bvb[8];
        LOADB(bva, 0)                  // first B batch behind the A loads
#pragma unroll
        for (int l = 0; l < 8; ++l)
            lds2[l * 128 + tid] = make_float2(a0[l], a1[l]);
        __syncthreads();

        float acc0[8], acc1[8];
#pragma unroll
        for (int l = 0; l < 8; ++l) { acc0[l] = 0.f; acc1[l] = 0.f; }

        // 16-batch software pipeline, 8 loads always in flight
        LOADB(bvb, 1)  FMAB(bva, 0)
        LOADB(bva, 2)  FMAB(bvb, 1)
        LOADB(bvb, 3)  FMAB(bva, 2)
        LOADB(bva, 4)  FMAB(bvb, 3)
        LOADB(bvb, 5)  FMAB(bva, 4)
        LOADB(bva, 6)  FMAB(bvb, 5)
        LOADB(bvb, 7)  FMAB(bva, 6)
        LOADB(bva, 8)  FMAB(bvb, 7)
        LOADB(bvb, 9)  FMAB(bva, 8)
        LOADB(bva,10)  FMAB(bvb, 9)
        LOADB(bvb,11)  FMAB(bva,10)
        LOADB(bva,12)  FMAB(bvb,11)
        LOADB(bvb,13)  FMAB(bva,12)
        LOADB(bva,14)  FMAB(bvb,13)
        LOADB(bvb,15)  FMAB(bva,14)
                       FMAB(bvb,15)

        // epilogue: C contraction; r1 = w*64+tl is lane-local, sum over 128
        // r1 = in-wave shfl reduce (both waves) + tiny LDS cross-wave add.
        const int r1 = w * 64 + tl;
#pragma unroll
        for (int l = 0; l < 8; ++l) {
            if (l < cl) {              // cl uniform -> no divergence
                const float* crow =
                    c2 + (size_t)(table * 216 + (s_aux[base + l] & 0xffff)) * 256;
                const float2 cv = *(const float2*)(crow + 2 * r1);
                float p00 = acc0[l] * cv.x;
                float p01 = acc0[l] * cv.y;
                float p10 = acc1[l] * cv.x;
                float p11 = acc1[l] * cv.y;
#pragma unroll
                for (int mm = 32; mm >= 1; mm >>= 1) {
                    p00 += __shfl_xor(p00, mm);
                    p01 += __shfl_xor(p01, mm);
                    p10 += __shfl_xor(p10, mm);
                    p11 += __shfl_xor(p11, mm);
                }
                if (tl == 0) {
                    red[w][l][0] = p00; red[w][l][1] = p01;
                    red[w][l][2] = p10; red[w][l][3] = p11;
                }
            }
        }
        __syncthreads();
        if (tid < 4 * cl) {
            const int l = tid >> 2, c = tid & 3;
            const int q0 = c >> 1, q2 = c & 1;     // out idx = q0*8 + q1*2 + q2
            out[(size_t)s_id[base + l] * 16 + q0 * 8 + q * 2 + q2] =
                red[0][l][c] + red[1][l][c];
        }
    }
#undef LOADB
#undef FMAB
}

extern "C" void kernel_launch(void* const* d_in, const int* in_sizes, int n_in,
                              void* d_out, int out_size, void* d_ws, size_t ws_size,
                              hipStream_t stream) {
    const int*   idx = (const int*)d_in[0];
    const float* c0  = (const float*)d_in[1];
    const float* c1  = (const float*)d_in[2];
    const float* c2  = (const float*)d_in[3];
    float* out = (float*)d_out;
    (void)d_ws; (void)ws_size; (void)in_sizes; (void)n_in; (void)out_size;

    tt_fused<<<dim3(432, 4, 2), dim3(128), 0, stream>>>(idx, c0, c1, c2, out);
}

// Round 8
// 183.066 us; speedup vs baseline: 6.4686x; 6.4686x over previous
//
#include <hip/hip_runtime.h>

// TT embedding lookup, fused single-kernel, wave-per-block, float4-wide.
// P=(216,216,216), Q=(2,4,2), R=(128,128), tables=2, batch=1024.
// core0: [2,216,256]   (A row:  [Q0=2][R0=128])
// core1: [2,216,65536] (Bm row: [R0=128][S=512], S = q1*128 + r1)
// core2: [2,216,256]   (C row:  [R1=128][Q2=2])
// out:   [2,1024,16]
//
// Round-7 lesson: __launch_bounds__ 2nd arg produced a 40-VGPR cap ->
// catastrophic scratch spill (WRITE 2.1 GB). Never force occupancy here.
//
// Round 1/3/5 invariant (68-76us at any occupancy, warm==cold): the
// A-broadcast ds_read_b128 stream. Broadcast still pays the LDS return
// path (1KB/wave-inst, ~8-12cyc); 512 reads/pass x 13.5 passes/CU ~ 35us
// of LDS-pipe serialization. Fix: lane owns FOUR s-columns (float4 acc) ->
// same FMA total, 1/4 the wave-passes, LDS reads/FLOP cut 4x.
//
// Grid (432 groups, 2 s-halves, 2 l-halves) x 64 threads (single wave,
// NO barriers; wave-order DS semantics). Wave: 256 s-cols, 4 rows/pass.
// B: float4 coalesced (1KB/inst), 2x4 register double-buffer.
// Deterministic ballot-scan binning (round-2 lesson: atomic order diverges
// across blocks; lh0/lh1 must see identical lists).

#define CAP  48          // Binomial(1024,1/216): mean 4.74, P(m>48) ~ 0
#define CAPP 52          // pad: s_aux[base+l] read blindly for l<4

__global__ __launch_bounds__(64) void tt_fused(
    const int* __restrict__ idx32,
    const float* __restrict__ c0,
    const float* __restrict__ c1,
    const float* __restrict__ c2,
    float* __restrict__ out)
{
    const int g     = blockIdx.x;      // group id [0,432) = table*216 + i1
    const int qh    = blockIdx.y;      // s-half {0,1}: s in [qh*256, qh*256+256)
    const int lh    = blockIdx.z;      // l-half {0,1}: rows base = lh*4 step 8
    const int table = g / 216;
    const int i1    = g - table * 216;
    const int tl    = threadIdx.x;     // 0..63

    __shared__ float lds[1024];        // A stage: [l<4][r<128] float2 (A0,A1)
    __shared__ int s_id[CAPP];
    __shared__ int s_aux[CAPP];        // (i0<<16)|i2 ; pad rows -> row 0

    if (tl < CAPP) s_aux[tl] = 0;

    // int64-vs-int32 buffer detection (values < 2^31 => odd words zero, LE)
    const bool is64 = (idx32[1] == 0) & (idx32[3] == 0) &
                      (idx32[5] == 0) & (idx32[7] == 0);

    // scan: 16 idx loads issued up-front, then VALU-only ballot placement
    unsigned v[16];
    if (is64) {
        const long long* p = (const long long*)idx32 + (table << 10) + tl;
#pragma unroll
        for (int it = 0; it < 16; ++it) v[it] = (unsigned)p[it * 64];
    } else {
        const int* p = idx32 + (table << 10) + tl;
#pragma unroll
        for (int it = 0; it < 16; ++it) v[it] = (unsigned)p[it * 64];
    }
    int cnt = 0;
#pragma unroll
    for (int it = 0; it < 16; ++it) {
        const unsigned idx = v[it];
        const unsigned i0  = idx / 46656u;           // magic-mul (idx < 2^24)
        const unsigned rem = idx - i0 * 46656u;
        const unsigned bi1 = rem / 216u;
        const bool match = ((int)bi1 == i1);
        const unsigned long long mask = __ballot(match);
        if (match) {
            const int pos = cnt + __popcll(mask & ((1ull << tl) - 1ull));
            if (pos < CAP) {
                const unsigned i2 = rem - bi1 * 216u;
                s_id[pos]  = (table << 10) + it * 64 + tl;
                s_aux[pos] = (int)((i0 << 16) | i2);
            }
        }
        cnt += (int)__popcll(mask);                  // uniform across wave
    }
    const int m = min(cnt, CAP);
    if (m <= lh * 4) return;           // lh1 exits unless m>4 (~43%)

    float2*       lds2 = (float2*)lds;
    const float4* lds4 = (const float4*)lds;

    // lane owns s = qh*256 + tl*4 .. +3; B row r at float4 index r*128
    const float4* b4  = (const float4*)(c1 + ((size_t)g << 16) + qh * 256) + tl;
    const float*  c0t = c0 + (size_t)table * 216 * 256;

#define LOADB(BUF, T)                                                       \
    { _Pragma("unroll")                                                     \
      for (int i = 0; i < 4; ++i) BUF[i] = b4[(size_t)((T) * 4 + i) * 128]; }

    // per (l,j): av=(A0[r],A1[r],A0[r+1],A1[r+1]) broadcast, r=T*4+2j
#define FMAB(BUF, T)                                                        \
    { _Pragma("unroll")                                                     \
      for (int l = 0; l < 4; ++l) {                                         \
        _Pragma("unroll")                                                   \
        for (int j = 0; j < 2; ++j) {                                       \
          const float4 av = lds4[l * 64 + (T) * 2 + j];                     \
          const float4 b0 = BUF[2 * j], b1 = BUF[2 * j + 1];                \
          acc0[l].x += av.x * b0.x; acc0[l].y += av.x * b0.y;               \
          acc0[l].z += av.x * b0.z; acc0[l].w += av.x * b0.w;               \
          acc0[l].x += av.z * b1.x; acc0[l].y += av.z * b1.y;               \
          acc0[l].z += av.z * b1.z; acc0[l].w += av.z * b1.w;               \
          acc1[l].x += av.y * b0.x; acc1[l].y += av.y * b0.y;               \
          acc1[l].z += av.y * b0.z; acc1[l].w += av.y * b0.w;               \
          acc1[l].x += av.w * b1.x; acc1[l].y += av.w * b1.y;               \
          acc1[l].z += av.w * b1.z; acc1[l].w += av.w * b1.w;               \
        } } }

    for (int base = lh * 4; base < m; base += 8) {
        const int cl = min(4, m - base);

        // stage A: 4 rows (pad -> row 0); coalesced 256B reads, b64 writes
#pragma unroll
        for (int l = 0; l < 4; ++l) {
            const float* ar = c0t + (size_t)(s_aux[base + l] >> 16) * 256;
            const float x0 = ar[tl],       x1 = ar[tl + 64];
            const float y0 = ar[tl + 128], y1 = ar[tl + 192];
            lds2[l * 128 + tl]      = make_float2(x0, y0);
            lds2[l * 128 + tl + 64] = make_float2(x1, y1);
        }

        float4 acc0[4], acc1[4];
#pragma unroll
        for (int l = 0; l < 4; ++l) {
            acc0[l] = make_float4(0.f, 0.f, 0.f, 0.f);
            acc1[l] = make_float4(0.f, 0.f, 0.f, 0.f);
        }

        // 32 batches of 4 r; 2-deep register double-buffer, no barriers
        float4 bufA[4], bufB[4];
        LOADB(bufA, 0)
        for (int T = 0; T < 30; T += 2) {
            LOADB(bufB, T + 1)
            FMAB(bufA, T)
            LOADB(bufA, T + 2)
            FMAB(bufB, T + 1)
        }
        LOADB(bufB, 31)
        FMAB(bufA, 30)
        FMAB(bufB, 31)

        // epilogue: lane's 4 s-cols are r1 = (tl&31)*4.. within q1 block
        const int half = tl >> 5;                    // q1 = qh*2 + half
        const int r1b  = (tl & 31) * 4;
#pragma unroll
        for (int l = 0; l < 4; ++l) {
            if (l < cl) {              // cl uniform -> no divergence
                const float* crow =
                    c2 + (size_t)(table * 216 + (s_aux[base + l] & 0xffff)) * 256;
                const float4 cv0 = *(const float4*)(crow + r1b * 2);
                const float4 cv1 = *(const float4*)(crow + r1b * 2 + 4);
                // cv0 = (C[r][0],C[r][1],C[r+1][0],C[r+1][1]), cv1 = r+2,r+3
                float p00 = acc0[l].x * cv0.x + acc0[l].y * cv0.z
                          + acc0[l].z * cv1.x + acc0[l].w * cv1.z;
                float p01 = acc0[l].x * cv0.y + acc0[l].y * cv0.w
                          + acc0[l].z * cv1.y + acc0[l].w * cv1.w;
                float p10 = acc1[l].x * cv0.x + acc1[l].y * cv0.z
                          + acc1[l].z * cv1.x + acc1[l].w * cv1.z;
                float p11 = acc1[l].x * cv0.y + acc1[l].y * cv0.w
                          + acc1[l].z * cv1.y + acc1[l].w * cv1.w;
#pragma unroll
                for (int mm = 16; mm >= 1; mm >>= 1) {   // within 32-lane half
                    p00 += __shfl_xor(p00, mm);
                    p01 += __shfl_xor(p01, mm);
                    p10 += __shfl_xor(p10, mm);
                    p11 += __shfl_xor(p11, mm);
                }
                if ((tl & 31) == 0) {
                    float* o = out + (size_t)s_id[base + l] * 16;
                    const int q1 = qh * 2 + half;
                    *(float2*)(o + q1 * 2)     = make_float2(p00, p01); // q0=0
                    *(float2*)(o + 8 + q1 * 2) = make_float2(p10, p11); // q0=1
                }
            }
        }
    }
#undef LOADB
#undef FMAB
}

extern "C" void kernel_launch(void* const* d_in, const int* in_sizes, int n_in,
                              void* d_out, int out_size, void* d_ws, size_t ws_size,
                              hipStream_t stream) {
    const int*   idx = (const int*)d_in[0];
    const float* c0  = (const float*)d_in[1];
    const float* c1  = (const float*)d_in[2];
    const float* c2  = (const float*)d_in[3];
    float* out = (float*)d_out;
    (void)d_ws; (void)ws_size; (void)in_sizes; (void)n_in; (void)out_size;

    tt_fused<<<dim3(432, 2, 2), dim3(64), 0, stream>>>(idx, c0, c1, c2, out);
}